// Round 14
// baseline (408.190 us; speedup 1.0000x reference)
//
#include <hip/hip_runtime.h>
#include <stdint.h>

typedef __attribute__((ext_vector_type(8))) short bf16x8;
typedef __attribute__((ext_vector_type(4))) float f32x4;
typedef unsigned short u16;

#define DEVINL static __device__ __forceinline__

namespace {
constexpr int kS = 2048, kD = 1024, kH = 16, kDK = 64;
constexpr int kBS = 4096, kBH = 32;
constexpr float kEps = 1e-5f;
// Q pre-scaled by (1/sqrt(dk)) * log2(e): scores live in exp2 domain.
constexpr float kQScale = 0.125f * 1.44269504088896340736f;
}

DEVINL u16 f2bf(float f) {   // round-to-nearest-even (cold paths)
  union { float f; unsigned u; } v; v.f = f;
  unsigned r = v.u + 0x7fffu + ((v.u >> 16) & 1u);
  return (u16)(r >> 16);
}
// pack two fp32 -> two bf16 (truncation; 2 VALU ops)
DEVINL unsigned pk2(float lo, float hi) {
  return (__float_as_uint(hi) & 0xffff0000u) | (__float_as_uint(lo) >> 16);
}
DEVINL f32x4 mfma16(bf16x8 a, bf16x8 b, f32x4 c) {
  return __builtin_amdgcn_mfma_f32_16x16x32_bf16(a, b, c, 0, 0, 0);
}

// ---------- pre-pass: X fp32 -> bf16 ----------
__global__ __launch_bounds__(256, 4)
void k_cvt_x(const float* __restrict__ xq, const float* __restrict__ xk,
             const float* __restrict__ xv, u16* __restrict__ oq,
             u16* __restrict__ ok, u16* __restrict__ ov) {
  const int z = blockIdx.y;
  const float* __restrict__ src = (z == 0) ? xq : (z == 1) ? xk : xv;
  u16* __restrict__ dst = (z == 0) ? oq : (z == 1) ? ok : ov;
  const size_t idx = (size_t)blockIdx.x * 256 + threadIdx.x;
  const float4 a = *reinterpret_cast<const float4*>(&src[idx * 8]);
  const float4 b = *reinterpret_cast<const float4*>(&src[idx * 8 + 4]);
  uint4 o;
  o.x = pk2(a.x, a.y); o.y = pk2(a.z, a.w);
  o.z = pk2(b.x, b.y); o.w = pk2(b.z, b.w);
  *reinterpret_cast<uint4*>(&dst[idx * 8]) = o;
}

// ---------- pre-pass: W [k][n] fp32 -> Wt [n][k] bf16 ----------
__global__ __launch_bounds__(256, 4)
void k_cvt_w(const float* __restrict__ wq, const float* __restrict__ wk,
             const float* __restrict__ wv, const float* __restrict__ wo,
             u16* __restrict__ oq, u16* __restrict__ ok,
             u16* __restrict__ ov, u16* __restrict__ oo) {
  const int z = blockIdx.z;
  const float* __restrict__ W = (z == 0) ? wq : (z == 1) ? wk : (z == 2) ? wv : wo;
  u16* __restrict__ Wt = (z == 0) ? oq : (z == 1) ? ok : (z == 2) ? ov : oo;
  const int n0 = blockIdx.x * 64, k0 = blockIdx.y * 64;
  const int tid = threadIdx.x;
  __shared__ u16 Tl[64][65];
#pragma unroll
  for (int p = 0; p < 4; ++p) {
    const int idx = tid + p * 256;
    const int kr = idx >> 4, cg = (idx & 15) * 4;
    const float4 v = *reinterpret_cast<const float4*>(&W[(size_t)(k0 + kr) * kD + n0 + cg]);
    Tl[kr][cg + 0] = f2bf(v.x);
    Tl[kr][cg + 1] = f2bf(v.y);
    Tl[kr][cg + 2] = f2bf(v.z);
    Tl[kr][cg + 3] = f2bf(v.w);
  }
  __syncthreads();
  const int n = tid >> 2, kc = (tid & 3) * 16;
  u16 buf[16];
#pragma unroll
  for (int i = 0; i < 16; ++i) buf[i] = Tl[kc + i][n];
  *reinterpret_cast<bf16x8*>(&Wt[(size_t)(n0 + n) * kD + k0 + kc]) =
      *reinterpret_cast<const bf16x8*>(&buf[0]);
  *reinterpret_cast<bf16x8*>(&Wt[(size_t)(n0 + n) * kD + k0 + kc + 8]) =
      *reinterpret_cast<const bf16x8*>(&buf[8]);
}

// ---------- QKV projection GEMM (bf16 in, bf16 out; reg-staged LDS) ----------
// grid (8, 32, 3), block 256.  Q,K -> [BH][S][64] ; V -> [BH][64][S] (transposed)
__global__ __launch_bounds__(256, 2)
void k_proj(const u16* __restrict__ Xq, const u16* __restrict__ Xk,
            const u16* __restrict__ Xv, const u16* __restrict__ Wtq,
            const u16* __restrict__ Wtk, const u16* __restrict__ Wtv,
            const float* __restrict__ bq, const float* __restrict__ bk,
            const float* __restrict__ bv, u16* __restrict__ Qo,
            u16* __restrict__ Ko, u16* __restrict__ Vo) {
  const int which = blockIdx.z;
  const u16* __restrict__ X = (which == 0) ? Xq : (which == 1) ? Xk : Xv;
  const u16* __restrict__ Wt = (which == 0) ? Wtq : (which == 1) ? Wtk : Wtv;
  const float* __restrict__ bias = (which == 0) ? bq : (which == 1) ? bk : bv;

  const int n0 = blockIdx.x * 128, m0 = blockIdx.y * 128;
  const int tid = threadIdx.x, w = tid >> 6, l = tid & 63;
  const int l15 = l & 15, lh = l >> 4;

  __shared__ u16 Al[128][72];
  __shared__ u16 Bl[128][72];

  f32x4 acc[2][8];
#pragma unroll
  for (int i = 0; i < 2; ++i)
#pragma unroll
    for (int j = 0; j < 8; ++j) acc[i][j] = f32x4{0.f, 0.f, 0.f, 0.f};

  for (int k0 = 0; k0 < kD; k0 += 64) {
    __syncthreads();
#pragma unroll
    for (int p = 0; p < 4; ++p) {
      const int idx = tid + p * 256;
      const int row = idx >> 3, c = (idx & 7) * 8;
      *reinterpret_cast<bf16x8*>(&Al[row][c]) =
          *reinterpret_cast<const bf16x8*>(&X[(size_t)(m0 + row) * kD + k0 + c]);
      *reinterpret_cast<bf16x8*>(&Bl[row][c]) =
          *reinterpret_cast<const bf16x8*>(&Wt[(size_t)(n0 + row) * kD + k0 + c]);
    }
    __syncthreads();
#pragma unroll
    for (int kq = 0; kq < 2; ++kq) {
      const int kk = kq * 32 + lh * 8;
      bf16x8 a[2], b[8];
#pragma unroll
      for (int mi = 0; mi < 2; ++mi)
        a[mi] = *reinterpret_cast<const bf16x8*>(&Al[w * 32 + mi * 16 + l15][kk]);
#pragma unroll
      for (int nj = 0; nj < 8; ++nj)
        b[nj] = *reinterpret_cast<const bf16x8*>(&Bl[nj * 16 + l15][kk]);
      if (which == 2) {
#pragma unroll
        for (int mi = 0; mi < 2; ++mi)
#pragma unroll
          for (int nj = 0; nj < 8; ++nj)
            acc[mi][nj] = mfma16(a[mi], b[nj], acc[mi][nj]);   // D: col=n, regs=m
      } else {
#pragma unroll
        for (int mi = 0; mi < 2; ++mi)
#pragma unroll
          for (int nj = 0; nj < 8; ++nj)
            acc[mi][nj] = mfma16(b[nj], a[mi], acc[mi][nj]);   // D: col=m, regs=n
      }
    }
  }

  if (which == 2) {
    // V transposed: lane holds 4 consecutive s for one d -> packed b64
#pragma unroll
    for (int mi = 0; mi < 2; ++mi)
#pragma unroll
      for (int nj = 0; nj < 8; ++nj) {
        const int col = n0 + nj * 16 + l15;
        const int h = col >> 6, d = col & 63;
        const float bvv = bias[col];
        const int row0 = m0 + w * 32 + mi * 16 + lh * 4;
        const int b_ = row0 >> 11, s0 = row0 & 2047;
        uint2 pkv;
        pkv.x = pk2(acc[mi][nj][0] + bvv, acc[mi][nj][1] + bvv);
        pkv.y = pk2(acc[mi][nj][2] + bvv, acc[mi][nj][3] + bvv);
        *reinterpret_cast<uint2*>(
            &Vo[((size_t)(b_ * kH + h) * kDK + d) * kS + s0]) = pkv;
      }
  } else {
    u16* __restrict__ Out = (which == 0) ? Qo : Ko;
    const float os = (which == 0) ? kQScale : 1.0f;
#pragma unroll
    for (int mi = 0; mi < 2; ++mi) {
      const int srow = m0 + w * 32 + mi * 16 + l15;
      const int b_ = srow >> 11, s_ = srow & 2047;
#pragma unroll
      for (int nj = 0; nj < 8; ++nj) {
        const int c0 = n0 + nj * 16 + lh * 4;     // 4 consecutive cols, one head
        const int h = c0 >> 6, d0 = c0 & 63;
        const float4 b4 = *reinterpret_cast<const float4*>(&bias[c0]);
        uint2 pkv;
        pkv.x = pk2((acc[mi][nj][0] + b4.x) * os, (acc[mi][nj][1] + b4.y) * os);
        pkv.y = pk2((acc[mi][nj][2] + b4.z) * os, (acc[mi][nj][3] + b4.w) * os);
        *reinterpret_cast<uint2*>(
            &Out[((size_t)(b_ * kH + h) * kS + s_) * kDK + d0]) = pkv;
      }
    }
  }
}

// ---------- fused attention (single-buffered K/V, 4 blocks/CU) ----------
// grid (16, 32), block 256 (4 waves). Reg-prefetch K/V; 2 barriers/tile;
// attn stored direct from regs; P wave-local. LDS 36.9KB -> occupancy 4.
__global__ __launch_bounds__(256, 4)
void k_attn(const u16* __restrict__ Qw, const u16* __restrict__ Kw,
            const u16* __restrict__ Vtw, float* __restrict__ attn_out,
            u16* __restrict__ ctx_out) {
  const int q0 = blockIdx.x * 128;
  const int bh = blockIdx.y;
  const int tid = threadIdx.x, w = tid >> 6, l = tid & 63;
  const int l15 = l & 15, lh = l >> 4;

  __shared__ u16 PQs[128][72];   // Q during init (consumed into regs), P afterwards
  __shared__ u16 Ksh[64][72];    // single-buffered
  __shared__ u16 Vsh[64][72];    // single-buffered

  const u16* __restrict__ Qg = Qw + ((size_t)bh * kS + q0) * kDK;
  const u16* __restrict__ Kg = Kw + (size_t)bh * kS * kDK;
  const u16* __restrict__ Vtg = Vtw + (size_t)bh * kDK * kS;

  const int srow = tid >> 2, sc = (tid & 3) * 16;  // staging: 64 rows x 64 cols, 2xb128/thread

  // stage Q
#pragma unroll
  for (int p = 0; p < 4; ++p) {
    const int idx = tid + p * 256;
    const int row = idx >> 3, c = (idx & 7) * 8;
    *reinterpret_cast<bf16x8*>(&PQs[row][c]) =
        *reinterpret_cast<const bf16x8*>(&Qg[(size_t)row * kDK + c]);
  }
  // stage K tile 0
  {
    const bf16x8 k0a = *reinterpret_cast<const bf16x8*>(&Kg[(size_t)srow * kDK + sc]);
    const bf16x8 k0b = *reinterpret_cast<const bf16x8*>(&Kg[(size_t)srow * kDK + sc + 8]);
    *reinterpret_cast<bf16x8*>(&Ksh[srow][sc]) = k0a;
    *reinterpret_cast<bf16x8*>(&Ksh[srow][sc + 8]) = k0b;
  }
  __syncthreads();

  // hoist Q fragments (B-operand; never re-read PQs as Q)
  bf16x8 qf[2][2];
#pragma unroll
  for (int mi = 0; mi < 2; ++mi)
#pragma unroll
    for (int kq = 0; kq < 2; ++kq)
      qf[mi][kq] = *reinterpret_cast<const bf16x8*>(
          &PQs[w * 32 + mi * 16 + l15][kq * 32 + lh * 8]);

  // ---- pass 1: row sums of exp2(S) ----
  bf16x8 kra, krb, vra, vrb;
  float lsum[2] = {0.f, 0.f};
  for (int t = 0; t < 32; ++t) {
    if (t + 1 < 32) {
      const u16* __restrict__ src = Kg + (size_t)(t + 1) * 64 * kDK;
      kra = *reinterpret_cast<const bf16x8*>(&src[(size_t)srow * kDK + sc]);
      krb = *reinterpret_cast<const bf16x8*>(&src[(size_t)srow * kDK + sc + 8]);
    }
    f32x4 sacc[2][4];
#pragma unroll
    for (int mi = 0; mi < 2; ++mi)
#pragma unroll
      for (int nj = 0; nj < 4; ++nj) sacc[mi][nj] = f32x4{0.f, 0.f, 0.f, 0.f};
    __builtin_amdgcn_s_setprio(1);
#pragma unroll
    for (int kq = 0; kq < 2; ++kq) {
      const int kk = kq * 32 + lh * 8;
      bf16x8 kf[4];
#pragma unroll
      for (int nj = 0; nj < 4; ++nj)
        kf[nj] = *reinterpret_cast<const bf16x8*>(&Ksh[nj * 16 + l15][kk]);
#pragma unroll
      for (int mi = 0; mi < 2; ++mi)
#pragma unroll
        for (int nj = 0; nj < 4; ++nj)
          sacc[mi][nj] = mfma16(kf[nj], qf[mi][kq], sacc[mi][nj]);
    }
    __builtin_amdgcn_s_setprio(0);
#pragma unroll
    for (int mi = 0; mi < 2; ++mi) {
      float s0 = 0.f;
#pragma unroll
      for (int nj = 0; nj < 4; ++nj)
#pragma unroll
        for (int r = 0; r < 4; ++r) s0 += exp2f(sacc[mi][nj][r]);
      lsum[mi] += s0;
    }
    __syncthreads();   // all reads of Ksh done
    if (t + 1 < 32) {
      *reinterpret_cast<bf16x8*>(&Ksh[srow][sc]) = kra;
      *reinterpret_cast<bf16x8*>(&Ksh[srow][sc + 8]) = krb;
    }
    __syncthreads();   // next tile staged
  }

  // merge kv-groups (lanes l, l^16, l^32, l^48 hold disjoint kv slices)
  float lg[2];
#pragma unroll
  for (int mi = 0; mi < 2; ++mi) {
    float lv = lsum[mi];
    lv += __shfl_xor(lv, 16, 64);
    lv += __shfl_xor(lv, 32, 64);
    lg[mi] = -log2f(lv);   // p = exp2(s + lg)
  }

  f32x4 oacc[2][4];
#pragma unroll
  for (int mi = 0; mi < 2; ++mi)
#pragma unroll
    for (int ni = 0; ni < 4; ++ni) oacc[mi][ni] = f32x4{0.f, 0.f, 0.f, 0.f};

  float* __restrict__ attn_base =
      attn_out + (size_t)bh * kS * kS + (size_t)q0 * kS;

  // stage tile 0 (K+V)
  {
    const bf16x8 k0a = *reinterpret_cast<const bf16x8*>(&Kg[(size_t)srow * kDK + sc]);
    const bf16x8 k0b = *reinterpret_cast<const bf16x8*>(&Kg[(size_t)srow * kDK + sc + 8]);
    const bf16x8 v0a = *reinterpret_cast<const bf16x8*>(&Vtg[(size_t)srow * kS + sc]);
    const bf16x8 v0b = *reinterpret_cast<const bf16x8*>(&Vtg[(size_t)srow * kS + sc + 8]);
    *reinterpret_cast<bf16x8*>(&Ksh[srow][sc]) = k0a;
    *reinterpret_cast<bf16x8*>(&Ksh[srow][sc + 8]) = k0b;
    *reinterpret_cast<bf16x8*>(&Vsh[srow][sc]) = v0a;
    *reinterpret_cast<bf16x8*>(&Vsh[srow][sc + 8]) = v0b;
  }
  __syncthreads();

  // ---- pass 2: recompute S; attn store from regs; wave-local P; PV ----
  for (int t = 0; t < 32; ++t) {
    const int t0 = t * 64;
    if (t + 1 < 32) {
      const u16* __restrict__ ksrc = Kg + (size_t)(t0 + 64) * kDK;
      kra = *reinterpret_cast<const bf16x8*>(&ksrc[(size_t)srow * kDK + sc]);
      krb = *reinterpret_cast<const bf16x8*>(&ksrc[(size_t)srow * kDK + sc + 8]);
      vra = *reinterpret_cast<const bf16x8*>(&Vtg[(size_t)srow * kS + t0 + 64 + sc]);
      vrb = *reinterpret_cast<const bf16x8*>(&Vtg[(size_t)srow * kS + t0 + 64 + sc + 8]);
    }
    f32x4 sacc[2][4];
#pragma unroll
    for (int mi = 0; mi < 2; ++mi)
#pragma unroll
      for (int nj = 0; nj < 4; ++nj) sacc[mi][nj] = f32x4{0.f, 0.f, 0.f, 0.f};
    __builtin_amdgcn_s_setprio(1);
#pragma unroll
    for (int kq = 0; kq < 2; ++kq) {
      const int kk = kq * 32 + lh * 8;
      bf16x8 kf[4];
#pragma unroll
      for (int nj = 0; nj < 4; ++nj)
        kf[nj] = *reinterpret_cast<const bf16x8*>(&Ksh[nj * 16 + l15][kk]);
#pragma unroll
      for (int mi = 0; mi < 2; ++mi)
#pragma unroll
        for (int nj = 0; nj < 4; ++nj)
          sacc[mi][nj] = mfma16(kf[nj], qf[mi][kq], sacc[mi][nj]);
    }
    __builtin_amdgcn_s_setprio(0);
    // p = exp2(s + lg): fp32 float4 straight to HBM + bf16 pack into wave-local PQs
#pragma unroll
    for (int mi = 0; mi < 2; ++mi) {
      const int q = w * 32 + mi * 16 + l15;
      float* __restrict__ arow = attn_base + (size_t)q * kS + t0;
#pragma unroll
      for (int nj = 0; nj < 4; ++nj) {
        float4 pv;
        pv.x = exp2f(sacc[mi][nj][0] + lg[mi]);
        pv.y = exp2f(sacc[mi][nj][1] + lg[mi]);
        pv.z = exp2f(sacc[mi][nj][2] + lg[mi]);
        pv.w = exp2f(sacc[mi][nj][3] + lg[mi]);
        *reinterpret_cast<float4*>(&arow[nj * 16 + lh * 4]) = pv;
        uint2 pkv; pkv.x = pk2(pv.x, pv.y); pkv.y = pk2(pv.z, pv.w);
        *reinterpret_cast<uint2*>(&PQs[q][nj * 16 + lh * 4]) = pkv;
      }
    }
    // PV: reads only this wave's PQs rows (wave-local; no barrier needed)
    __builtin_amdgcn_s_setprio(1);
#pragma unroll
    for (int kq = 0; kq < 2; ++kq) {
      const int kk = kq * 32 + lh * 8;
      bf16x8 pa[2], vb[4];
#pragma unroll
      for (int mi = 0; mi < 2; ++mi)
        pa[mi] = *reinterpret_cast<const bf16x8*>(&PQs[w * 32 + mi * 16 + l15][kk]);
#pragma unroll
      for (int ni = 0; ni < 4; ++ni)
        vb[ni] = *reinterpret_cast<const bf16x8*>(&Vsh[ni * 16 + l15][kk]);
#pragma unroll
      for (int mi = 0; mi < 2; ++mi)
#pragma unroll
        for (int ni = 0; ni < 4; ++ni)
          oacc[mi][ni] = mfma16(vb[ni], pa[mi], oacc[mi][ni]);
    }
    __builtin_amdgcn_s_setprio(0);
    __syncthreads();   // all reads of Ksh/Vsh done
    if (t + 1 < 32) {
      *reinterpret_cast<bf16x8*>(&Ksh[srow][sc]) = kra;
      *reinterpret_cast<bf16x8*>(&Ksh[srow][sc + 8]) = krb;
      *reinterpret_cast<bf16x8*>(&Vsh[srow][sc]) = vra;
      *reinterpret_cast<bf16x8*>(&Vsh[srow][sc + 8]) = vrb;
    }
    __syncthreads();   // next tile staged
  }

  // ctx -> ws bf16 [BS][D]; lane has 4 consecutive d -> packed b64
  const int b_ = bh >> 4, h = bh & 15;
#pragma unroll
  for (int mi = 0; mi < 2; ++mi) {
    const int s_ = q0 + w * 32 + mi * 16 + l15;
#pragma unroll
    for (int ni = 0; ni < 4; ++ni) {
      const int d0 = ni * 16 + lh * 4;
      uint2 pkv;
      pkv.x = pk2(oacc[mi][ni][0], oacc[mi][ni][1]);
      pkv.y = pk2(oacc[mi][ni][2], oacc[mi][ni][3]);
      *reinterpret_cast<uint2*>(
          &ctx_out[((size_t)(b_ * kS + s_)) * kD + h * kDK + d0]) = pkv;
    }
  }
}

// ---------- out projection + bias + residual ----------
__global__ __launch_bounds__(256, 2)
void k_oproj(const u16* __restrict__ Cw, const u16* __restrict__ Wto,
             const float* __restrict__ bo, const float* __restrict__ query,
             float* __restrict__ Xout) {
  const int n0 = blockIdx.x * 128, m0 = blockIdx.y * 128;
  const int tid = threadIdx.x, w = tid >> 6, l = tid & 63;
  const int l15 = l & 15, lh = l >> 4;

  __shared__ u16 Al[128][72];
  __shared__ u16 Bl[128][72];

  f32x4 acc[2][8];
#pragma unroll
  for (int i = 0; i < 2; ++i)
#pragma unroll
    for (int j = 0; j < 8; ++j) acc[i][j] = f32x4{0.f, 0.f, 0.f, 0.f};

  for (int k0 = 0; k0 < kD; k0 += 64) {
    __syncthreads();
#pragma unroll
    for (int p = 0; p < 4; ++p) {
      const int idx = tid + p * 256;
      const int row = idx >> 3, c = (idx & 7) * 8;
      *reinterpret_cast<bf16x8*>(&Al[row][c]) =
          *reinterpret_cast<const bf16x8*>(&Cw[(size_t)(m0 + row) * kD + k0 + c]);
      *reinterpret_cast<bf16x8*>(&Bl[row][c]) =
          *reinterpret_cast<const bf16x8*>(&Wto[(size_t)(n0 + row) * kD + k0 + c]);
    }
    __syncthreads();
#pragma unroll
    for (int kq = 0; kq < 2; ++kq) {
      const int kk = kq * 32 + lh * 8;
      bf16x8 a[2], b[8];
#pragma unroll
      for (int mi = 0; mi < 2; ++mi)
        a[mi] = *reinterpret_cast<const bf16x8*>(&Al[w * 32 + mi * 16 + l15][kk]);
#pragma unroll
      for (int nj = 0; nj < 8; ++nj)
        b[nj] = *reinterpret_cast<const bf16x8*>(&Bl[nj * 16 + l15][kk]);
#pragma unroll
      for (int mi = 0; mi < 2; ++mi)
#pragma unroll
        for (int nj = 0; nj < 8; ++nj)
          acc[mi][nj] = mfma16(b[nj], a[mi], acc[mi][nj]);   // col=m, regs=n
    }
  }

#pragma unroll
  for (int mi = 0; mi < 2; ++mi) {
    const int row = m0 + w * 32 + mi * 16 + l15;
#pragma unroll
    for (int nj = 0; nj < 8; ++nj) {
      const int c0 = n0 + nj * 16 + lh * 4;
      const float4 b4 = *reinterpret_cast<const float4*>(&bo[c0]);
      const float4 q4 = *reinterpret_cast<const float4*>(&query[(size_t)row * kD + c0]);
      float4 o;
      o.x = acc[mi][nj][0] + b4.x + q4.x;
      o.y = acc[mi][nj][1] + b4.y + q4.y;
      o.z = acc[mi][nj][2] + b4.z + q4.z;
      o.w = acc[mi][nj][3] + b4.w + q4.w;
      *reinterpret_cast<float4*>(&Xout[(size_t)row * kD + c0]) = o;
    }
  }
}

// ---------- LayerNorm (in place) ----------
__global__ __launch_bounds__(256, 4)
void k_ln(float* __restrict__ Y, const float* __restrict__ gamma,
          const float* __restrict__ beta) {
  const int row = blockIdx.x;
  float* __restrict__ x = Y + (size_t)row * kD;
  const int tid = threadIdx.x;
  const float4 v = reinterpret_cast<const float4*>(x)[tid];
  float s = v.x + v.y + v.z + v.w;
  float sq = v.x * v.x + v.y * v.y + v.z * v.z + v.w * v.w;
#pragma unroll
  for (int mk = 1; mk < 64; mk <<= 1) {
    s += __shfl_xor(s, mk, 64);
    sq += __shfl_xor(sq, mk, 64);
  }
  __shared__ float ss[4], ssq[4];
  if ((tid & 63) == 0) { ss[tid >> 6] = s; ssq[tid >> 6] = sq; }
  __syncthreads();
  s = ss[0] + ss[1] + ss[2] + ss[3];
  sq = ssq[0] + ssq[1] + ssq[2] + ssq[3];
  const float mu = s * (1.f / kD);
  const float rstd = rsqrtf(sq * (1.f / kD) - mu * mu + kEps);
  const float4 g = reinterpret_cast<const float4*>(gamma)[tid];
  const float4 bb = reinterpret_cast<const float4*>(beta)[tid];
  float4 o;
  o.x = (v.x - mu) * rstd * g.x + bb.x;
  o.y = (v.y - mu) * rstd * g.y + bb.y;
  o.z = (v.z - mu) * rstd * g.z + bb.z;
  o.w = (v.w - mu) * rstd * g.w + bb.w;
  reinterpret_cast<float4*>(x)[tid] = o;
}

extern "C" void kernel_launch(void* const* d_in, const int* in_sizes, int n_in,
                              void* d_out, int out_size, void* d_ws, size_t ws_size,
                              hipStream_t stream) {
  (void)in_sizes; (void)n_in; (void)out_size; (void)ws_size;
  const float* query = (const float*)d_in[0];
  const float* key_i = (const float*)d_in[1];
  const float* value = (const float*)d_in[2];
  const float* Wq = (const float*)d_in[3];
  const float* bq = (const float*)d_in[4];
  const float* Wk = (const float*)d_in[5];
  const float* bk = (const float*)d_in[6];
  const float* Wv = (const float*)d_in[7];
  const float* bv = (const float*)d_in[8];
  const float* Wo = (const float*)d_in[9];
  const float* bo = (const float*)d_in[10];
  const float* gamma = (const float*)d_in[11];
  const float* beta = (const float*)d_in[12];

  float* y_out = (float*)d_out;                       // [2,2048,1024]
  float* attn_out = y_out + (size_t)kBS * kD;         // [2,16,2048,2048]

  u16* Xbq = (u16*)d_ws;
  u16* Xbk = Xbq + (size_t)kBS * kD;
  u16* Xbv = Xbk + (size_t)kBS * kD;
  u16* Wtq = Xbv + (size_t)kBS * kD;
  u16* Wtk = Wtq + (size_t)kD * kD;
  u16* Wtv = Wtk + (size_t)kD * kD;
  u16* Wto = Wtv + (size_t)kD * kD;
  u16* Qw  = Wto + (size_t)kD * kD;
  u16* Kw  = Qw + (size_t)kBH * kS * kDK;
  u16* Vtw = Kw + (size_t)kBH * kS * kDK;
  u16* Cw  = Xbq;   // alias: Xbq dead after k_proj

  k_cvt_x<<<dim3(2048, 3), 256, 0, stream>>>(query, key_i, value, Xbq, Xbk, Xbv);
  k_cvt_w<<<dim3(16, 16, 4), 256, 0, stream>>>(Wq, Wk, Wv, Wo, Wtq, Wtk, Wtv, Wto);
  k_proj<<<dim3(kD / 128, kBS / 128, 3), 256, 0, stream>>>(
      Xbq, Xbk, Xbv, Wtq, Wtk, Wtv, bq, bk, bv, Qw, Kw, Vtw);
  k_attn<<<dim3(kS / 128, kBH), 256, 0, stream>>>(Qw, Kw, Vtw, attn_out, Cw);
  k_oproj<<<dim3(kD / 128, kBS / 128), 256, 0, stream>>>(Cw, Wto, bo, query, y_out);
  k_ln<<<dim3(kBS), 256, 0, stream>>>(y_out, gamma, beta);
}

// Round 15
// 321.118 us; speedup vs baseline: 1.2712x; 1.2712x over previous
//
#include <hip/hip_runtime.h>
#include <stdint.h>

typedef __attribute__((ext_vector_type(8))) short bf16x8;
typedef __attribute__((ext_vector_type(4))) float f32x4;
typedef unsigned short u16;

#define DEVINL static __device__ __forceinline__

namespace {
constexpr int kS = 2048, kD = 1024, kH = 16, kDK = 64;
constexpr int kBS = 4096, kBH = 32;
constexpr float kEps = 1e-5f;
// Q pre-scaled by (1/sqrt(dk)) * log2(e): scores live in exp2 domain.
constexpr float kQScale = 0.125f * 1.44269504088896340736f;
}

DEVINL u16 f2bf(float f) {   // round-to-nearest-even (cold paths)
  union { float f; unsigned u; } v; v.f = f;
  unsigned r = v.u + 0x7fffu + ((v.u >> 16) & 1u);
  return (u16)(r >> 16);
}
// pack two fp32 -> two bf16 (truncation; 2 VALU ops)
DEVINL unsigned pk2(float lo, float hi) {
  return (__float_as_uint(hi) & 0xffff0000u) | (__float_as_uint(lo) >> 16);
}
DEVINL f32x4 mfma16(bf16x8 a, bf16x8 b, f32x4 c) {
  return __builtin_amdgcn_mfma_f32_16x16x32_bf16(a, b, c, 0, 0, 0);
}

// ---------- pre-pass: X fp32 -> bf16 ----------
__global__ __launch_bounds__(256, 4)
void k_cvt_x(const float* __restrict__ xq, const float* __restrict__ xk,
             const float* __restrict__ xv, u16* __restrict__ oq,
             u16* __restrict__ ok, u16* __restrict__ ov) {
  const int z = blockIdx.y;
  const float* __restrict__ src = (z == 0) ? xq : (z == 1) ? xk : xv;
  u16* __restrict__ dst = (z == 0) ? oq : (z == 1) ? ok : ov;
  const size_t idx = (size_t)blockIdx.x * 256 + threadIdx.x;
  const float4 a = *reinterpret_cast<const float4*>(&src[idx * 8]);
  const float4 b = *reinterpret_cast<const float4*>(&src[idx * 8 + 4]);
  uint4 o;
  o.x = pk2(a.x, a.y); o.y = pk2(a.z, a.w);
  o.z = pk2(b.x, b.y); o.w = pk2(b.z, b.w);
  *reinterpret_cast<uint4*>(&dst[idx * 8]) = o;
}

// ---------- pre-pass: W [k][n] fp32 -> Wt [n][k] bf16 ----------
__global__ __launch_bounds__(256, 4)
void k_cvt_w(const float* __restrict__ wq, const float* __restrict__ wk,
             const float* __restrict__ wv, const float* __restrict__ wo,
             u16* __restrict__ oq, u16* __restrict__ ok,
             u16* __restrict__ ov, u16* __restrict__ oo) {
  const int z = blockIdx.z;
  const float* __restrict__ W = (z == 0) ? wq : (z == 1) ? wk : (z == 2) ? wv : wo;
  u16* __restrict__ Wt = (z == 0) ? oq : (z == 1) ? ok : (z == 2) ? ov : oo;
  const int n0 = blockIdx.x * 64, k0 = blockIdx.y * 64;
  const int tid = threadIdx.x;
  __shared__ u16 Tl[64][65];
#pragma unroll
  for (int p = 0; p < 4; ++p) {
    const int idx = tid + p * 256;
    const int kr = idx >> 4, cg = (idx & 15) * 4;
    const float4 v = *reinterpret_cast<const float4*>(&W[(size_t)(k0 + kr) * kD + n0 + cg]);
    Tl[kr][cg + 0] = f2bf(v.x);
    Tl[kr][cg + 1] = f2bf(v.y);
    Tl[kr][cg + 2] = f2bf(v.z);
    Tl[kr][cg + 3] = f2bf(v.w);
  }
  __syncthreads();
  const int n = tid >> 2, kc = (tid & 3) * 16;
  u16 buf[16];
#pragma unroll
  for (int i = 0; i < 16; ++i) buf[i] = Tl[kc + i][n];
  *reinterpret_cast<bf16x8*>(&Wt[(size_t)(n0 + n) * kD + k0 + kc]) =
      *reinterpret_cast<const bf16x8*>(&buf[0]);
  *reinterpret_cast<bf16x8*>(&Wt[(size_t)(n0 + n) * kD + k0 + kc + 8]) =
      *reinterpret_cast<const bf16x8*>(&buf[8]);
}

// ---------- QKV projection GEMM (bf16 in, bf16 out; reg-staged LDS) ----------
// grid (8, 32, 3), block 256.  Q,K -> [BH][S][64] ; V -> [BH][64][S] (transposed)
__global__ __launch_bounds__(256, 2)
void k_proj(const u16* __restrict__ Xq, const u16* __restrict__ Xk,
            const u16* __restrict__ Xv, const u16* __restrict__ Wtq,
            const u16* __restrict__ Wtk, const u16* __restrict__ Wtv,
            const float* __restrict__ bq, const float* __restrict__ bk,
            const float* __restrict__ bv, u16* __restrict__ Qo,
            u16* __restrict__ Ko, u16* __restrict__ Vo) {
  const int which = blockIdx.z;
  const u16* __restrict__ X = (which == 0) ? Xq : (which == 1) ? Xk : Xv;
  const u16* __restrict__ Wt = (which == 0) ? Wtq : (which == 1) ? Wtk : Wtv;
  const float* __restrict__ bias = (which == 0) ? bq : (which == 1) ? bk : bv;

  const int n0 = blockIdx.x * 128, m0 = blockIdx.y * 128;
  const int tid = threadIdx.x, w = tid >> 6, l = tid & 63;
  const int l15 = l & 15, lh = l >> 4;

  __shared__ u16 Al[128][72];
  __shared__ u16 Bl[128][72];

  f32x4 acc[2][8];
#pragma unroll
  for (int i = 0; i < 2; ++i)
#pragma unroll
    for (int j = 0; j < 8; ++j) acc[i][j] = f32x4{0.f, 0.f, 0.f, 0.f};

  for (int k0 = 0; k0 < kD; k0 += 64) {
    __syncthreads();
#pragma unroll
    for (int p = 0; p < 4; ++p) {
      const int idx = tid + p * 256;
      const int row = idx >> 3, c = (idx & 7) * 8;
      *reinterpret_cast<bf16x8*>(&Al[row][c]) =
          *reinterpret_cast<const bf16x8*>(&X[(size_t)(m0 + row) * kD + k0 + c]);
      *reinterpret_cast<bf16x8*>(&Bl[row][c]) =
          *reinterpret_cast<const bf16x8*>(&Wt[(size_t)(n0 + row) * kD + k0 + c]);
    }
    __syncthreads();
#pragma unroll
    for (int kq = 0; kq < 2; ++kq) {
      const int kk = kq * 32 + lh * 8;
      bf16x8 a[2], b[8];
#pragma unroll
      for (int mi = 0; mi < 2; ++mi)
        a[mi] = *reinterpret_cast<const bf16x8*>(&Al[w * 32 + mi * 16 + l15][kk]);
#pragma unroll
      for (int nj = 0; nj < 8; ++nj)
        b[nj] = *reinterpret_cast<const bf16x8*>(&Bl[nj * 16 + l15][kk]);
      if (which == 2) {
#pragma unroll
        for (int mi = 0; mi < 2; ++mi)
#pragma unroll
          for (int nj = 0; nj < 8; ++nj)
            acc[mi][nj] = mfma16(a[mi], b[nj], acc[mi][nj]);   // D: col=n, regs=m
      } else {
#pragma unroll
        for (int mi = 0; mi < 2; ++mi)
#pragma unroll
          for (int nj = 0; nj < 8; ++nj)
            acc[mi][nj] = mfma16(b[nj], a[mi], acc[mi][nj]);   // D: col=m, regs=n
      }
    }
  }

  if (which == 2) {
    // V transposed: lane holds 4 consecutive s for one d -> packed b64
#pragma unroll
    for (int mi = 0; mi < 2; ++mi)
#pragma unroll
      for (int nj = 0; nj < 8; ++nj) {
        const int col = n0 + nj * 16 + l15;
        const int h = col >> 6, d = col & 63;
        const float bvv = bias[col];
        const int row0 = m0 + w * 32 + mi * 16 + lh * 4;
        const int b_ = row0 >> 11, s0 = row0 & 2047;
        uint2 pkv;
        pkv.x = pk2(acc[mi][nj][0] + bvv, acc[mi][nj][1] + bvv);
        pkv.y = pk2(acc[mi][nj][2] + bvv, acc[mi][nj][3] + bvv);
        *reinterpret_cast<uint2*>(
            &Vo[((size_t)(b_ * kH + h) * kDK + d) * kS + s0]) = pkv;
      }
  } else {
    u16* __restrict__ Out = (which == 0) ? Qo : Ko;
    const float os = (which == 0) ? kQScale : 1.0f;
#pragma unroll
    for (int mi = 0; mi < 2; ++mi) {
      const int srow = m0 + w * 32 + mi * 16 + l15;
      const int b_ = srow >> 11, s_ = srow & 2047;
#pragma unroll
      for (int nj = 0; nj < 8; ++nj) {
        const int c0 = n0 + nj * 16 + lh * 4;     // 4 consecutive cols, one head
        const int h = c0 >> 6, d0 = c0 & 63;
        const float4 b4 = *reinterpret_cast<const float4*>(&bias[c0]);
        uint2 pkv;
        pkv.x = pk2((acc[mi][nj][0] + b4.x) * os, (acc[mi][nj][1] + b4.y) * os);
        pkv.y = pk2((acc[mi][nj][2] + b4.z) * os, (acc[mi][nj][3] + b4.w) * os);
        *reinterpret_cast<uint2*>(
            &Out[((size_t)(b_ * kH + h) * kS + s_) * kDK + d0]) = pkv;
      }
    }
  }
}

// ---------- fused attention (swapped QK^T, exp2 domain, reg-staged dbuf) ----------
// grid (16, 32), block 256 (4 waves). Pass 2: attn stored direct from regs,
// P is wave-local -> ONE barrier per tile. No setprio (lockstep waves; m190 regime).
__global__ __launch_bounds__(256, 2)
void k_attn(const u16* __restrict__ Qw, const u16* __restrict__ Kw,
            const u16* __restrict__ Vtw, float* __restrict__ attn_out,
            u16* __restrict__ ctx_out) {
  const int q0 = blockIdx.x * 128;
  const int bh = blockIdx.y;
  const int tid = threadIdx.x, w = tid >> 6, l = tid & 63;
  const int l15 = l & 15, lh = l >> 4;

  __shared__ u16 PQs[128][72];     // Q during init (consumed into regs), P afterwards
  __shared__ u16 Ksh[2][64][72];
  __shared__ u16 Vsh[2][64][72];

  const u16* __restrict__ Qg = Qw + ((size_t)bh * kS + q0) * kDK;
  const u16* __restrict__ Kg = Kw + (size_t)bh * kS * kDK;
  const u16* __restrict__ Vtg = Vtw + (size_t)bh * kDK * kS;

  // stage Q
#pragma unroll
  for (int p = 0; p < 4; ++p) {
    const int idx = tid + p * 256;
    const int row = idx >> 3, c = (idx & 7) * 8;
    *reinterpret_cast<bf16x8*>(&PQs[row][c]) =
        *reinterpret_cast<const bf16x8*>(&Qg[(size_t)row * kDK + c]);
  }
  // preload K tile 0 -> Ksh[0]
  bf16x8 kreg[2], vreg[2];
#pragma unroll
  for (int p = 0; p < 2; ++p) {
    const int idx = tid + p * 256;
    const int row = idx >> 3, c = (idx & 7) * 8;
    kreg[p] = *reinterpret_cast<const bf16x8*>(&Kg[(size_t)row * kDK + c]);
  }
#pragma unroll
  for (int p = 0; p < 2; ++p) {
    const int idx = tid + p * 256;
    const int row = idx >> 3, c = (idx & 7) * 8;
    *reinterpret_cast<bf16x8*>(&Ksh[0][row][c]) = kreg[p];
  }
  __syncthreads();

  // hoist Q fragments (B-operand; never re-read PQs as Q)
  bf16x8 qf[2][2];
#pragma unroll
  for (int mi = 0; mi < 2; ++mi)
#pragma unroll
    for (int kq = 0; kq < 2; ++kq)
      qf[mi][kq] = *reinterpret_cast<const bf16x8*>(
          &PQs[w * 32 + mi * 16 + l15][kq * 32 + lh * 8]);

  // ---- pass 1: row sums of exp2(S); one barrier per tile ----
  float lsum[2] = {0.f, 0.f};
  for (int t = 0; t < 32; ++t) {
    const int buf = t & 1;
    if (t + 1 < 32) {
      const u16* __restrict__ src = Kg + (size_t)(t + 1) * 64 * kDK;
#pragma unroll
      for (int p = 0; p < 2; ++p) {
        const int idx = tid + p * 256;
        const int row = idx >> 3, c = (idx & 7) * 8;
        kreg[p] = *reinterpret_cast<const bf16x8*>(&src[(size_t)row * kDK + c]);
      }
    }
    f32x4 sacc[2][4];
#pragma unroll
    for (int mi = 0; mi < 2; ++mi)
#pragma unroll
      for (int nj = 0; nj < 4; ++nj) sacc[mi][nj] = f32x4{0.f, 0.f, 0.f, 0.f};
#pragma unroll
    for (int kq = 0; kq < 2; ++kq) {
      const int kk = kq * 32 + lh * 8;
      bf16x8 kf[4];
#pragma unroll
      for (int nj = 0; nj < 4; ++nj)
        kf[nj] = *reinterpret_cast<const bf16x8*>(&Ksh[buf][nj * 16 + l15][kk]);
#pragma unroll
      for (int mi = 0; mi < 2; ++mi)
#pragma unroll
        for (int nj = 0; nj < 4; ++nj)
          sacc[mi][nj] = mfma16(kf[nj], qf[mi][kq], sacc[mi][nj]);
    }
#pragma unroll
    for (int mi = 0; mi < 2; ++mi) {
      float s0 = 0.f;
#pragma unroll
      for (int nj = 0; nj < 4; ++nj)
#pragma unroll
        for (int r = 0; r < 4; ++r) s0 += exp2f(sacc[mi][nj][r]);
      lsum[mi] += s0;
    }
    if (t + 1 < 32) {
#pragma unroll
      for (int p = 0; p < 2; ++p) {
        const int idx = tid + p * 256;
        const int row = idx >> 3, c = (idx & 7) * 8;
        *reinterpret_cast<bf16x8*>(&Ksh[buf ^ 1][row][c]) = kreg[p];
      }
    }
    __syncthreads();
  }

  // merge kv-groups (lanes l, l^16, l^32, l^48 hold disjoint kv slices)
  float lg[2];
#pragma unroll
  for (int mi = 0; mi < 2; ++mi) {
    float lv = lsum[mi];
    lv += __shfl_xor(lv, 16, 64);
    lv += __shfl_xor(lv, 32, 64);
    lg[mi] = -log2f(lv);   // p = exp2(s + lg)
  }

  f32x4 oacc[2][4];
#pragma unroll
  for (int mi = 0; mi < 2; ++mi)
#pragma unroll
    for (int ni = 0; ni < 4; ++ni) oacc[mi][ni] = f32x4{0.f, 0.f, 0.f, 0.f};

  float* __restrict__ attn_base =
      attn_out + (size_t)bh * kS * kS + (size_t)q0 * kS;

  // preload tile 0 (K+V) -> buf 0
#pragma unroll
  for (int p = 0; p < 2; ++p) {
    const int idx = tid + p * 256;
    const int row = idx >> 3, c = (idx & 7) * 8;
    kreg[p] = *reinterpret_cast<const bf16x8*>(&Kg[(size_t)row * kDK + c]);
    vreg[p] = *reinterpret_cast<const bf16x8*>(&Vtg[(size_t)row * kS + c]);
  }
#pragma unroll
  for (int p = 0; p < 2; ++p) {
    const int idx = tid + p * 256;
    const int row = idx >> 3, c = (idx & 7) * 8;
    *reinterpret_cast<bf16x8*>(&Ksh[0][row][c]) = kreg[p];
    *reinterpret_cast<bf16x8*>(&Vsh[0][row][c]) = vreg[p];
  }
  __syncthreads();

  // ---- pass 2: recompute S; attn store direct from regs; wave-local P; PV ----
  for (int t = 0; t < 32; ++t) {
    const int buf = t & 1;
    const int t0 = t * 64;
    if (t + 1 < 32) {
      const u16* __restrict__ ksrc = Kg + (size_t)(t0 + 64) * kDK;
#pragma unroll
      for (int p = 0; p < 2; ++p) {
        const int idx = tid + p * 256;
        const int row = idx >> 3, c = (idx & 7) * 8;
        kreg[p] = *reinterpret_cast<const bf16x8*>(&ksrc[(size_t)row * kDK + c]);
        vreg[p] = *reinterpret_cast<const bf16x8*>(&Vtg[(size_t)row * kS + t0 + 64 + c]);
      }
    }
    f32x4 sacc[2][4];
#pragma unroll
    for (int mi = 0; mi < 2; ++mi)
#pragma unroll
      for (int nj = 0; nj < 4; ++nj) sacc[mi][nj] = f32x4{0.f, 0.f, 0.f, 0.f};
#pragma unroll
    for (int kq = 0; kq < 2; ++kq) {
      const int kk = kq * 32 + lh * 8;
      bf16x8 kf[4];
#pragma unroll
      for (int nj = 0; nj < 4; ++nj)
        kf[nj] = *reinterpret_cast<const bf16x8*>(&Ksh[buf][nj * 16 + l15][kk]);
#pragma unroll
      for (int mi = 0; mi < 2; ++mi)
#pragma unroll
        for (int nj = 0; nj < 4; ++nj)
          sacc[mi][nj] = mfma16(kf[nj], qf[mi][kq], sacc[mi][nj]);
    }
    // p = exp2(s + lg): fp32 float4 straight to HBM (lane quad = 16B, lh
    // quads complete 64B lines) + bf16 pack into wave-local PQs rows.
#pragma unroll
    for (int mi = 0; mi < 2; ++mi) {
      const int q = w * 32 + mi * 16 + l15;
      float* __restrict__ arow = attn_base + (size_t)q * kS + t0;
#pragma unroll
      for (int nj = 0; nj < 4; ++nj) {
        float4 pv;
        pv.x = exp2f(sacc[mi][nj][0] + lg[mi]);
        pv.y = exp2f(sacc[mi][nj][1] + lg[mi]);
        pv.z = exp2f(sacc[mi][nj][2] + lg[mi]);
        pv.w = exp2f(sacc[mi][nj][3] + lg[mi]);
        *reinterpret_cast<float4*>(&arow[nj * 16 + lh * 4]) = pv;
        uint2 pkv; pkv.x = pk2(pv.x, pv.y); pkv.y = pk2(pv.z, pv.w);
        *reinterpret_cast<uint2*>(&PQs[q][nj * 16 + lh * 4]) = pkv;
      }
    }
    // PV: reads only this wave's PQs rows (LDS ops in-order within wave; no barrier)
#pragma unroll
    for (int kq = 0; kq < 2; ++kq) {
      const int kk = kq * 32 + lh * 8;
      bf16x8 pa[2], vb[4];
#pragma unroll
      for (int mi = 0; mi < 2; ++mi)
        pa[mi] = *reinterpret_cast<const bf16x8*>(&PQs[w * 32 + mi * 16 + l15][kk]);
#pragma unroll
      for (int ni = 0; ni < 4; ++ni)
        vb[ni] = *reinterpret_cast<const bf16x8*>(&Vsh[buf][ni * 16 + l15][kk]);
#pragma unroll
      for (int mi = 0; mi < 2; ++mi)
#pragma unroll
        for (int ni = 0; ni < 4; ++ni)
          oacc[mi][ni] = mfma16(vb[ni], pa[mi], oacc[mi][ni]);
    }
    if (t + 1 < 32) {
#pragma unroll
      for (int p = 0; p < 2; ++p) {
        const int idx = tid + p * 256;
        const int row = idx >> 3, c = (idx & 7) * 8;
        *reinterpret_cast<bf16x8*>(&Ksh[buf ^ 1][row][c]) = kreg[p];
        *reinterpret_cast<bf16x8*>(&Vsh[buf ^ 1][row][c]) = vreg[p];
      }
    }
    __syncthreads();   // single barrier: K/V dbuf handoff
  }

  // ctx -> ws bf16 [BS][D]; lane has 4 consecutive d -> packed b64
  const int b_ = bh >> 4, h = bh & 15;
#pragma unroll
  for (int mi = 0; mi < 2; ++mi) {
    const int s_ = q0 + w * 32 + mi * 16 + l15;
#pragma unroll
    for (int ni = 0; ni < 4; ++ni) {
      const int d0 = ni * 16 + lh * 4;
      uint2 pkv;
      pkv.x = pk2(oacc[mi][ni][0], oacc[mi][ni][1]);
      pkv.y = pk2(oacc[mi][ni][2], oacc[mi][ni][3]);
      *reinterpret_cast<uint2*>(
          &ctx_out[((size_t)(b_ * kS + s_)) * kD + h * kDK + d0]) = pkv;
    }
  }
}

// ---------- out projection + bias + residual ----------
__global__ __launch_bounds__(256, 2)
void k_oproj(const u16* __restrict__ Cw, const u16* __restrict__ Wto,
             const float* __restrict__ bo, const float* __restrict__ query,
             float* __restrict__ Xout) {
  const int n0 = blockIdx.x * 128, m0 = blockIdx.y * 128;
  const int tid = threadIdx.x, w = tid >> 6, l = tid & 63;
  const int l15 = l & 15, lh = l >> 4;

  __shared__ u16 Al[128][72];
  __shared__ u16 Bl[128][72];

  f32x4 acc[2][8];
#pragma unroll
  for (int i = 0; i < 2; ++i)
#pragma unroll
    for (int j = 0; j < 8; ++j) acc[i][j] = f32x4{0.f, 0.f, 0.f, 0.f};

  for (int k0 = 0; k0 < kD; k0 += 64) {
    __syncthreads();
#pragma unroll
    for (int p = 0; p < 4; ++p) {
      const int idx = tid + p * 256;
      const int row = idx >> 3, c = (idx & 7) * 8;
      *reinterpret_cast<bf16x8*>(&Al[row][c]) =
          *reinterpret_cast<const bf16x8*>(&Cw[(size_t)(m0 + row) * kD + k0 + c]);
      *reinterpret_cast<bf16x8*>(&Bl[row][c]) =
          *reinterpret_cast<const bf16x8*>(&Wto[(size_t)(n0 + row) * kD + k0 + c]);
    }
    __syncthreads();
#pragma unroll
    for (int kq = 0; kq < 2; ++kq) {
      const int kk = kq * 32 + lh * 8;
      bf16x8 a[2], b[8];
#pragma unroll
      for (int mi = 0; mi < 2; ++mi)
        a[mi] = *reinterpret_cast<const bf16x8*>(&Al[w * 32 + mi * 16 + l15][kk]);
#pragma unroll
      for (int nj = 0; nj < 8; ++nj)
        b[nj] = *reinterpret_cast<const bf16x8*>(&Bl[nj * 16 + l15][kk]);
#pragma unroll
      for (int mi = 0; mi < 2; ++mi)
#pragma unroll
        for (int nj = 0; nj < 8; ++nj)
          acc[mi][nj] = mfma16(b[nj], a[mi], acc[mi][nj]);   // col=m, regs=n
    }
  }

#pragma unroll
  for (int mi = 0; mi < 2; ++mi) {
    const int row = m0 + w * 32 + mi * 16 + l15;
#pragma unroll
    for (int nj = 0; nj < 8; ++nj) {
      const int c0 = n0 + nj * 16 + lh * 4;
      const float4 b4 = *reinterpret_cast<const float4*>(&bo[c0]);
      const float4 q4 = *reinterpret_cast<const float4*>(&query[(size_t)row * kD + c0]);
      float4 o;
      o.x = acc[mi][nj][0] + b4.x + q4.x;
      o.y = acc[mi][nj][1] + b4.y + q4.y;
      o.z = acc[mi][nj][2] + b4.z + q4.z;
      o.w = acc[mi][nj][3] + b4.w + q4.w;
      *reinterpret_cast<float4*>(&Xout[(size_t)row * kD + c0]) = o;
    }
  }
}

// ---------- LayerNorm (in place) ----------
__global__ __launch_bounds__(256, 4)
void k_ln(float* __restrict__ Y, const float* __restrict__ gamma,
          const float* __restrict__ beta) {
  const int row = blockIdx.x;
  float* __restrict__ x = Y + (size_t)row * kD;
  const int tid = threadIdx.x;
  const float4 v = reinterpret_cast<const float4*>(x)[tid];
  float s = v.x + v.y + v.z + v.w;
  float sq = v.x * v.x + v.y * v.y + v.z * v.z + v.w * v.w;
#pragma unroll
  for (int mk = 1; mk < 64; mk <<= 1) {
    s += __shfl_xor(s, mk, 64);
    sq += __shfl_xor(sq, mk, 64);
  }
  __shared__ float ss[4], ssq[4];
  if ((tid & 63) == 0) { ss[tid >> 6] = s; ssq[tid >> 6] = sq; }
  __syncthreads();
  s = ss[0] + ss[1] + ss[2] + ss[3];
  sq = ssq[0] + ssq[1] + ssq[2] + ssq[3];
  const float mu = s * (1.f / kD);
  const float rstd = rsqrtf(sq * (1.f / kD) - mu * mu + kEps);
  const float4 g = reinterpret_cast<const float4*>(gamma)[tid];
  const float4 bb = reinterpret_cast<const float4*>(beta)[tid];
  float4 o;
  o.x = (v.x - mu) * rstd * g.x + bb.x;
  o.y = (v.y - mu) * rstd * g.y + bb.y;
  o.z = (v.z - mu) * rstd * g.z + bb.z;
  o.w = (v.w - mu) * rstd * g.w + bb.w;
  reinterpret_cast<float4*>(x)[tid] = o;
}

extern "C" void kernel_launch(void* const* d_in, const int* in_sizes, int n_in,
                              void* d_out, int out_size, void* d_ws, size_t ws_size,
                              hipStream_t stream) {
  (void)in_sizes; (void)n_in; (void)out_size; (void)ws_size;
  const float* query = (const float*)d_in[0];
  const float* key_i = (const float*)d_in[1];
  const float* value = (const float*)d_in[2];
  const float* Wq = (const float*)d_in[3];
  const float* bq = (const float*)d_in[4];
  const float* Wk = (const float*)d_in[5];
  const float* bk = (const float*)d_in[6];
  const float* Wv = (const float*)d_in[7];
  const float* bv = (const float*)d_in[8];
  const float* Wo = (const float*)d_in[9];
  const float* bo = (const float*)d_in[10];
  const float* gamma = (const float*)d_in[11];
  const float* beta = (const float*)d_in[12];

  float* y_out = (float*)d_out;                       // [2,2048,1024]
  float* attn_out = y_out + (size_t)kBS * kD;         // [2,16,2048,2048]

  u16* Xbq = (u16*)d_ws;
  u16* Xbk = Xbq + (size_t)kBS * kD;
  u16* Xbv = Xbk + (size_t)kBS * kD;
  u16* Wtq = Xbv + (size_t)kBS * kD;
  u16* Wtk = Wtq + (size_t)kD * kD;
  u16* Wtv = Wtk + (size_t)kD * kD;
  u16* Wto = Wtv + (size_t)kD * kD;
  u16* Qw  = Wto + (size_t)kD * kD;
  u16* Kw  = Qw + (size_t)kBH * kS * kDK;
  u16* Vtw = Kw + (size_t)kBH * kS * kDK;
  u16* Cw  = Xbq;   // alias: Xbq dead after k_proj

  k_cvt_x<<<dim3(2048, 3), 256, 0, stream>>>(query, key_i, value, Xbq, Xbk, Xbv);
  k_cvt_w<<<dim3(16, 16, 4), 256, 0, stream>>>(Wq, Wk, Wv, Wo, Wtq, Wtk, Wtv, Wto);
  k_proj<<<dim3(kD / 128, kBS / 128, 3), 256, 0, stream>>>(
      Xbq, Xbk, Xbv, Wtq, Wtk, Wtv, bq, bk, bv, Qw, Kw, Vtw);
  k_attn<<<dim3(kS / 128, kBH), 256, 0, stream>>>(Qw, Kw, Vtw, attn_out, Cw);
  k_oproj<<<dim3(kD / 128, kBS / 128), 256, 0, stream>>>(Cw, Wto, bo, query, y_out);
  k_ln<<<dim3(kBS), 256, 0, stream>>>(y_out, gamma, beta);
}

// Round 16
// 314.527 us; speedup vs baseline: 1.2978x; 1.0210x over previous
//
#include <hip/hip_runtime.h>
#include <stdint.h>

typedef __attribute__((ext_vector_type(8))) short bf16x8;
typedef __attribute__((ext_vector_type(4))) float f32x4;
typedef unsigned short u16;

#define DEVINL static __device__ __forceinline__

namespace {
constexpr int kS = 2048, kD = 1024, kH = 16, kDK = 64;
constexpr int kBS = 4096, kBH = 32;
constexpr float kEps = 1e-5f;
// Q pre-scaled by (1/sqrt(dk)) * log2(e): scores live in exp2 domain.
constexpr float kQScale = 0.125f * 1.44269504088896340736f;
}

DEVINL u16 f2bf(float f) {   // round-to-nearest-even (cold paths)
  union { float f; unsigned u; } v; v.f = f;
  unsigned r = v.u + 0x7fffu + ((v.u >> 16) & 1u);
  return (u16)(r >> 16);
}
// pack two fp32 -> two bf16 (truncation; 2 VALU ops)
DEVINL unsigned pk2(float lo, float hi) {
  return (__float_as_uint(hi) & 0xffff0000u) | (__float_as_uint(lo) >> 16);
}
DEVINL f32x4 mfma16(bf16x8 a, bf16x8 b, f32x4 c) {
  return __builtin_amdgcn_mfma_f32_16x16x32_bf16(a, b, c, 0, 0, 0);
}

// ---------- pre-pass: X fp32 -> bf16 ----------
__global__ __launch_bounds__(256, 4)
void k_cvt_x(const float* __restrict__ xq, const float* __restrict__ xk,
             const float* __restrict__ xv, u16* __restrict__ oq,
             u16* __restrict__ ok, u16* __restrict__ ov) {
  const int z = blockIdx.y;
  const float* __restrict__ src = (z == 0) ? xq : (z == 1) ? xk : xv;
  u16* __restrict__ dst = (z == 0) ? oq : (z == 1) ? ok : ov;
  const size_t idx = (size_t)blockIdx.x * 256 + threadIdx.x;
  const float4 a = *reinterpret_cast<const float4*>(&src[idx * 8]);
  const float4 b = *reinterpret_cast<const float4*>(&src[idx * 8 + 4]);
  uint4 o;
  o.x = pk2(a.x, a.y); o.y = pk2(a.z, a.w);
  o.z = pk2(b.x, b.y); o.w = pk2(b.z, b.w);
  *reinterpret_cast<uint4*>(&dst[idx * 8]) = o;
}

// ---------- pre-pass: W [k][n] fp32 -> Wt [n][k] bf16 ----------
__global__ __launch_bounds__(256, 4)
void k_cvt_w(const float* __restrict__ wq, const float* __restrict__ wk,
             const float* __restrict__ wv, const float* __restrict__ wo,
             u16* __restrict__ oq, u16* __restrict__ ok,
             u16* __restrict__ ov, u16* __restrict__ oo) {
  const int z = blockIdx.z;
  const float* __restrict__ W = (z == 0) ? wq : (z == 1) ? wk : (z == 2) ? wv : wo;
  u16* __restrict__ Wt = (z == 0) ? oq : (z == 1) ? ok : (z == 2) ? ov : oo;
  const int n0 = blockIdx.x * 64, k0 = blockIdx.y * 64;
  const int tid = threadIdx.x;
  __shared__ u16 Tl[64][65];
#pragma unroll
  for (int p = 0; p < 4; ++p) {
    const int idx = tid + p * 256;
    const int kr = idx >> 4, cg = (idx & 15) * 4;
    const float4 v = *reinterpret_cast<const float4*>(&W[(size_t)(k0 + kr) * kD + n0 + cg]);
    Tl[kr][cg + 0] = f2bf(v.x);
    Tl[kr][cg + 1] = f2bf(v.y);
    Tl[kr][cg + 2] = f2bf(v.z);
    Tl[kr][cg + 3] = f2bf(v.w);
  }
  __syncthreads();
  const int n = tid >> 2, kc = (tid & 3) * 16;
  u16 buf[16];
#pragma unroll
  for (int i = 0; i < 16; ++i) buf[i] = Tl[kc + i][n];
  *reinterpret_cast<bf16x8*>(&Wt[(size_t)(n0 + n) * kD + k0 + kc]) =
      *reinterpret_cast<const bf16x8*>(&buf[0]);
  *reinterpret_cast<bf16x8*>(&Wt[(size_t)(n0 + n) * kD + k0 + kc + 8]) =
      *reinterpret_cast<const bf16x8*>(&buf[8]);
}

// ---------- QKV projection GEMM (bf16 in, bf16 out; reg-staged LDS) ----------
// grid (8, 32, 3), block 256.  Q,K -> [BH][S][64] ; V -> [BH][64][S] (transposed)
__global__ __launch_bounds__(256, 2)
void k_proj(const u16* __restrict__ Xq, const u16* __restrict__ Xk,
            const u16* __restrict__ Xv, const u16* __restrict__ Wtq,
            const u16* __restrict__ Wtk, const u16* __restrict__ Wtv,
            const float* __restrict__ bq, const float* __restrict__ bk,
            const float* __restrict__ bv, u16* __restrict__ Qo,
            u16* __restrict__ Ko, u16* __restrict__ Vo) {
  const int which = blockIdx.z;
  const u16* __restrict__ X = (which == 0) ? Xq : (which == 1) ? Xk : Xv;
  const u16* __restrict__ Wt = (which == 0) ? Wtq : (which == 1) ? Wtk : Wtv;
  const float* __restrict__ bias = (which == 0) ? bq : (which == 1) ? bk : bv;

  const int n0 = blockIdx.x * 128, m0 = blockIdx.y * 128;
  const int tid = threadIdx.x, w = tid >> 6, l = tid & 63;
  const int l15 = l & 15, lh = l >> 4;

  __shared__ u16 Al[128][72];
  __shared__ u16 Bl[128][72];

  f32x4 acc[2][8];
#pragma unroll
  for (int i = 0; i < 2; ++i)
#pragma unroll
    for (int j = 0; j < 8; ++j) acc[i][j] = f32x4{0.f, 0.f, 0.f, 0.f};

  for (int k0 = 0; k0 < kD; k0 += 64) {
    __syncthreads();
#pragma unroll
    for (int p = 0; p < 4; ++p) {
      const int idx = tid + p * 256;
      const int row = idx >> 3, c = (idx & 7) * 8;
      *reinterpret_cast<bf16x8*>(&Al[row][c]) =
          *reinterpret_cast<const bf16x8*>(&X[(size_t)(m0 + row) * kD + k0 + c]);
      *reinterpret_cast<bf16x8*>(&Bl[row][c]) =
          *reinterpret_cast<const bf16x8*>(&Wt[(size_t)(n0 + row) * kD + k0 + c]);
    }
    __syncthreads();
#pragma unroll
    for (int kq = 0; kq < 2; ++kq) {
      const int kk = kq * 32 + lh * 8;
      bf16x8 a[2], b[8];
#pragma unroll
      for (int mi = 0; mi < 2; ++mi)
        a[mi] = *reinterpret_cast<const bf16x8*>(&Al[w * 32 + mi * 16 + l15][kk]);
#pragma unroll
      for (int nj = 0; nj < 8; ++nj)
        b[nj] = *reinterpret_cast<const bf16x8*>(&Bl[nj * 16 + l15][kk]);
      if (which == 2) {
#pragma unroll
        for (int mi = 0; mi < 2; ++mi)
#pragma unroll
          for (int nj = 0; nj < 8; ++nj)
            acc[mi][nj] = mfma16(a[mi], b[nj], acc[mi][nj]);   // D: col=n, regs=m
      } else {
#pragma unroll
        for (int mi = 0; mi < 2; ++mi)
#pragma unroll
          for (int nj = 0; nj < 8; ++nj)
            acc[mi][nj] = mfma16(b[nj], a[mi], acc[mi][nj]);   // D: col=m, regs=n
      }
    }
  }

  if (which == 2) {
    // V transposed: lane holds 4 consecutive s for one d -> packed b64
#pragma unroll
    for (int mi = 0; mi < 2; ++mi)
#pragma unroll
      for (int nj = 0; nj < 8; ++nj) {
        const int col = n0 + nj * 16 + l15;
        const int h = col >> 6, d = col & 63;
        const float bvv = bias[col];
        const int row0 = m0 + w * 32 + mi * 16 + lh * 4;
        const int b_ = row0 >> 11, s0 = row0 & 2047;
        uint2 pkv;
        pkv.x = pk2(acc[mi][nj][0] + bvv, acc[mi][nj][1] + bvv);
        pkv.y = pk2(acc[mi][nj][2] + bvv, acc[mi][nj][3] + bvv);
        *reinterpret_cast<uint2*>(
            &Vo[((size_t)(b_ * kH + h) * kDK + d) * kS + s0]) = pkv;
      }
  } else {
    u16* __restrict__ Out = (which == 0) ? Qo : Ko;
    const float os = (which == 0) ? kQScale : 1.0f;
#pragma unroll
    for (int mi = 0; mi < 2; ++mi) {
      const int srow = m0 + w * 32 + mi * 16 + l15;
      const int b_ = srow >> 11, s_ = srow & 2047;
#pragma unroll
      for (int nj = 0; nj < 8; ++nj) {
        const int c0 = n0 + nj * 16 + lh * 4;     // 4 consecutive cols, one head
        const int h = c0 >> 6, d0 = c0 & 63;
        const float4 b4 = *reinterpret_cast<const float4*>(&bias[c0]);
        uint2 pkv;
        pkv.x = pk2((acc[mi][nj][0] + b4.x) * os, (acc[mi][nj][1] + b4.y) * os);
        pkv.y = pk2((acc[mi][nj][2] + b4.z) * os, (acc[mi][nj][3] + b4.w) * os);
        *reinterpret_cast<uint2*>(
            &Out[((size_t)(b_ * kH + h) * kS + s_) * kDK + d0]) = pkv;
      }
    }
  }
}

// ---------- fused attention (swapped QK^T, exp2 domain, reg-staged dbuf) ----------
// grid (16, 32), block 256 (4 waves). Pass 2: attn stored direct from regs,
// P is wave-local -> ONE barrier per tile.
__global__ __launch_bounds__(256, 2)
void k_attn(const u16* __restrict__ Qw, const u16* __restrict__ Kw,
            const u16* __restrict__ Vtw, float* __restrict__ attn_out,
            u16* __restrict__ ctx_out) {
  const int q0 = blockIdx.x * 128;
  const int bh = blockIdx.y;
  const int tid = threadIdx.x, w = tid >> 6, l = tid & 63;
  const int l15 = l & 15, lh = l >> 4;

  __shared__ u16 PQs[128][72];     // Q during init (consumed into regs), P afterwards
  __shared__ u16 Ksh[2][64][72];
  __shared__ u16 Vsh[2][64][72];

  const u16* __restrict__ Qg = Qw + ((size_t)bh * kS + q0) * kDK;
  const u16* __restrict__ Kg = Kw + (size_t)bh * kS * kDK;
  const u16* __restrict__ Vtg = Vtw + (size_t)bh * kDK * kS;

  // stage Q
#pragma unroll
  for (int p = 0; p < 4; ++p) {
    const int idx = tid + p * 256;
    const int row = idx >> 3, c = (idx & 7) * 8;
    *reinterpret_cast<bf16x8*>(&PQs[row][c]) =
        *reinterpret_cast<const bf16x8*>(&Qg[(size_t)row * kDK + c]);
  }
  // preload K tile 0 -> Ksh[0]
  bf16x8 kreg[2], vreg[2];
#pragma unroll
  for (int p = 0; p < 2; ++p) {
    const int idx = tid + p * 256;
    const int row = idx >> 3, c = (idx & 7) * 8;
    kreg[p] = *reinterpret_cast<const bf16x8*>(&Kg[(size_t)row * kDK + c]);
  }
#pragma unroll
  for (int p = 0; p < 2; ++p) {
    const int idx = tid + p * 256;
    const int row = idx >> 3, c = (idx & 7) * 8;
    *reinterpret_cast<bf16x8*>(&Ksh[0][row][c]) = kreg[p];
  }
  __syncthreads();

  // hoist Q fragments (B-operand; never re-read PQs as Q)
  bf16x8 qf[2][2];
#pragma unroll
  for (int mi = 0; mi < 2; ++mi)
#pragma unroll
    for (int kq = 0; kq < 2; ++kq)
      qf[mi][kq] = *reinterpret_cast<const bf16x8*>(
          &PQs[w * 32 + mi * 16 + l15][kq * 32 + lh * 8]);

  // ---- pass 1: row sums of exp2(S); one barrier per tile ----
  float lsum[2] = {0.f, 0.f};
  for (int t = 0; t < 32; ++t) {
    const int buf = t & 1;
    if (t + 1 < 32) {
      const u16* __restrict__ src = Kg + (size_t)(t + 1) * 64 * kDK;
#pragma unroll
      for (int p = 0; p < 2; ++p) {
        const int idx = tid + p * 256;
        const int row = idx >> 3, c = (idx & 7) * 8;
        kreg[p] = *reinterpret_cast<const bf16x8*>(&src[(size_t)row * kDK + c]);
      }
    }
    f32x4 sacc[2][4];
#pragma unroll
    for (int mi = 0; mi < 2; ++mi)
#pragma unroll
      for (int nj = 0; nj < 4; ++nj) sacc[mi][nj] = f32x4{0.f, 0.f, 0.f, 0.f};
    __builtin_amdgcn_s_setprio(1);
#pragma unroll
    for (int kq = 0; kq < 2; ++kq) {
      const int kk = kq * 32 + lh * 8;
      bf16x8 kf[4];
#pragma unroll
      for (int nj = 0; nj < 4; ++nj)
        kf[nj] = *reinterpret_cast<const bf16x8*>(&Ksh[buf][nj * 16 + l15][kk]);
#pragma unroll
      for (int mi = 0; mi < 2; ++mi)
#pragma unroll
        for (int nj = 0; nj < 4; ++nj)
          sacc[mi][nj] = mfma16(kf[nj], qf[mi][kq], sacc[mi][nj]);
    }
    __builtin_amdgcn_s_setprio(0);
#pragma unroll
    for (int mi = 0; mi < 2; ++mi) {
      float s0 = 0.f;
#pragma unroll
      for (int nj = 0; nj < 4; ++nj)
#pragma unroll
        for (int r = 0; r < 4; ++r) s0 += exp2f(sacc[mi][nj][r]);
      lsum[mi] += s0;
    }
    if (t + 1 < 32) {
#pragma unroll
      for (int p = 0; p < 2; ++p) {
        const int idx = tid + p * 256;
        const int row = idx >> 3, c = (idx & 7) * 8;
        *reinterpret_cast<bf16x8*>(&Ksh[buf ^ 1][row][c]) = kreg[p];
      }
    }
    __syncthreads();
  }

  // merge kv-groups (lanes l, l^16, l^32, l^48 hold disjoint kv slices)
  float lg[2];
#pragma unroll
  for (int mi = 0; mi < 2; ++mi) {
    float lv = lsum[mi];
    lv += __shfl_xor(lv, 16, 64);
    lv += __shfl_xor(lv, 32, 64);
    lg[mi] = -log2f(lv);   // p = exp2(s + lg)
  }

  f32x4 oacc[2][4];
#pragma unroll
  for (int mi = 0; mi < 2; ++mi)
#pragma unroll
    for (int ni = 0; ni < 4; ++ni) oacc[mi][ni] = f32x4{0.f, 0.f, 0.f, 0.f};

  float* __restrict__ attn_base =
      attn_out + (size_t)bh * kS * kS + (size_t)q0 * kS;

  // preload tile 0 (K+V) -> buf 0
#pragma unroll
  for (int p = 0; p < 2; ++p) {
    const int idx = tid + p * 256;
    const int row = idx >> 3, c = (idx & 7) * 8;
    kreg[p] = *reinterpret_cast<const bf16x8*>(&Kg[(size_t)row * kDK + c]);
    vreg[p] = *reinterpret_cast<const bf16x8*>(&Vtg[(size_t)row * kS + c]);
  }
#pragma unroll
  for (int p = 0; p < 2; ++p) {
    const int idx = tid + p * 256;
    const int row = idx >> 3, c = (idx & 7) * 8;
    *reinterpret_cast<bf16x8*>(&Ksh[0][row][c]) = kreg[p];
    *reinterpret_cast<bf16x8*>(&Vsh[0][row][c]) = vreg[p];
  }
  __syncthreads();

  // ---- pass 2: recompute S; attn store direct from regs; wave-local P; PV ----
  for (int t = 0; t < 32; ++t) {
    const int buf = t & 1;
    const int t0 = t * 64;
    if (t + 1 < 32) {
      const u16* __restrict__ ksrc = Kg + (size_t)(t0 + 64) * kDK;
#pragma unroll
      for (int p = 0; p < 2; ++p) {
        const int idx = tid + p * 256;
        const int row = idx >> 3, c = (idx & 7) * 8;
        kreg[p] = *reinterpret_cast<const bf16x8*>(&ksrc[(size_t)row * kDK + c]);
        vreg[p] = *reinterpret_cast<const bf16x8*>(&Vtg[(size_t)row * kS + t0 + 64 + c]);
      }
    }
    f32x4 sacc[2][4];
#pragma unroll
    for (int mi = 0; mi < 2; ++mi)
#pragma unroll
      for (int nj = 0; nj < 4; ++nj) sacc[mi][nj] = f32x4{0.f, 0.f, 0.f, 0.f};
    __builtin_amdgcn_s_setprio(1);
#pragma unroll
    for (int kq = 0; kq < 2; ++kq) {
      const int kk = kq * 32 + lh * 8;
      bf16x8 kf[4];
#pragma unroll
      for (int nj = 0; nj < 4; ++nj)
        kf[nj] = *reinterpret_cast<const bf16x8*>(&Ksh[buf][nj * 16 + l15][kk]);
#pragma unroll
      for (int mi = 0; mi < 2; ++mi)
#pragma unroll
        for (int nj = 0; nj < 4; ++nj)
          sacc[mi][nj] = mfma16(kf[nj], qf[mi][kq], sacc[mi][nj]);
    }
    __builtin_amdgcn_s_setprio(0);
    // p = exp2(s + lg): fp32 float4 straight to HBM (lane quad = 16B, lh
    // quads complete 64B lines) + bf16 pack into wave-local PQs rows.
#pragma unroll
    for (int mi = 0; mi < 2; ++mi) {
      const int q = w * 32 + mi * 16 + l15;
      float* __restrict__ arow = attn_base + (size_t)q * kS + t0;
#pragma unroll
      for (int nj = 0; nj < 4; ++nj) {
        float4 pv;
        pv.x = exp2f(sacc[mi][nj][0] + lg[mi]);
        pv.y = exp2f(sacc[mi][nj][1] + lg[mi]);
        pv.z = exp2f(sacc[mi][nj][2] + lg[mi]);
        pv.w = exp2f(sacc[mi][nj][3] + lg[mi]);
        *reinterpret_cast<float4*>(&arow[nj * 16 + lh * 4]) = pv;
        uint2 pkv; pkv.x = pk2(pv.x, pv.y); pkv.y = pk2(pv.z, pv.w);
        *reinterpret_cast<uint2*>(&PQs[q][nj * 16 + lh * 4]) = pkv;
      }
    }
    // PV: reads only this wave's PQs rows (LDS ops in-order within wave; no barrier)
    __builtin_amdgcn_s_setprio(1);
#pragma unroll
    for (int kq = 0; kq < 2; ++kq) {
      const int kk = kq * 32 + lh * 8;
      bf16x8 pa[2], vb[4];
#pragma unroll
      for (int mi = 0; mi < 2; ++mi)
        pa[mi] = *reinterpret_cast<const bf16x8*>(&PQs[w * 32 + mi * 16 + l15][kk]);
#pragma unroll
      for (int ni = 0; ni < 4; ++ni)
        vb[ni] = *reinterpret_cast<const bf16x8*>(&Vsh[buf][ni * 16 + l15][kk]);
#pragma unroll
      for (int mi = 0; mi < 2; ++mi)
#pragma unroll
        for (int ni = 0; ni < 4; ++ni)
          oacc[mi][ni] = mfma16(vb[ni], pa[mi], oacc[mi][ni]);
    }
    __builtin_amdgcn_s_setprio(0);
    if (t + 1 < 32) {
#pragma unroll
      for (int p = 0; p < 2; ++p) {
        const int idx = tid + p * 256;
        const int row = idx >> 3, c = (idx & 7) * 8;
        *reinterpret_cast<bf16x8*>(&Ksh[buf ^ 1][row][c]) = kreg[p];
        *reinterpret_cast<bf16x8*>(&Vsh[buf ^ 1][row][c]) = vreg[p];
      }
    }
    __syncthreads();   // single barrier: K/V dbuf handoff
  }

  // ctx -> ws bf16 [BS][D]; lane has 4 consecutive d -> packed b64
  const int b_ = bh >> 4, h = bh & 15;
#pragma unroll
  for (int mi = 0; mi < 2; ++mi) {
    const int s_ = q0 + w * 32 + mi * 16 + l15;
#pragma unroll
    for (int ni = 0; ni < 4; ++ni) {
      const int d0 = ni * 16 + lh * 4;
      uint2 pkv;
      pkv.x = pk2(oacc[mi][ni][0], oacc[mi][ni][1]);
      pkv.y = pk2(oacc[mi][ni][2], oacc[mi][ni][3]);
      *reinterpret_cast<uint2*>(
          &ctx_out[((size_t)(b_ * kS + s_)) * kD + h * kDK + d0]) = pkv;
    }
  }
}

// ---------- out projection + bias + residual ----------
__global__ __launch_bounds__(256, 2)
void k_oproj(const u16* __restrict__ Cw, const u16* __restrict__ Wto,
             const float* __restrict__ bo, const float* __restrict__ query,
             float* __restrict__ Xout) {
  const int n0 = blockIdx.x * 128, m0 = blockIdx.y * 128;
  const int tid = threadIdx.x, w = tid >> 6, l = tid & 63;
  const int l15 = l & 15, lh = l >> 4;

  __shared__ u16 Al[128][72];
  __shared__ u16 Bl[128][72];

  f32x4 acc[2][8];
#pragma unroll
  for (int i = 0; i < 2; ++i)
#pragma unroll
    for (int j = 0; j < 8; ++j) acc[i][j] = f32x4{0.f, 0.f, 0.f, 0.f};

  for (int k0 = 0; k0 < kD; k0 += 64) {
    __syncthreads();
#pragma unroll
    for (int p = 0; p < 4; ++p) {
      const int idx = tid + p * 256;
      const int row = idx >> 3, c = (idx & 7) * 8;
      *reinterpret_cast<bf16x8*>(&Al[row][c]) =
          *reinterpret_cast<const bf16x8*>(&Cw[(size_t)(m0 + row) * kD + k0 + c]);
      *reinterpret_cast<bf16x8*>(&Bl[row][c]) =
          *reinterpret_cast<const bf16x8*>(&Wto[(size_t)(n0 + row) * kD + k0 + c]);
    }
    __syncthreads();
#pragma unroll
    for (int kq = 0; kq < 2; ++kq) {
      const int kk = kq * 32 + lh * 8;
      bf16x8 a[2], b[8];
#pragma unroll
      for (int mi = 0; mi < 2; ++mi)
        a[mi] = *reinterpret_cast<const bf16x8*>(&Al[w * 32 + mi * 16 + l15][kk]);
#pragma unroll
      for (int nj = 0; nj < 8; ++nj)
        b[nj] = *reinterpret_cast<const bf16x8*>(&Bl[nj * 16 + l15][kk]);
#pragma unroll
      for (int mi = 0; mi < 2; ++mi)
#pragma unroll
        for (int nj = 0; nj < 8; ++nj)
          acc[mi][nj] = mfma16(b[nj], a[mi], acc[mi][nj]);   // col=m, regs=n
    }
  }

#pragma unroll
  for (int mi = 0; mi < 2; ++mi) {
    const int row = m0 + w * 32 + mi * 16 + l15;
#pragma unroll
    for (int nj = 0; nj < 8; ++nj) {
      const int c0 = n0 + nj * 16 + lh * 4;
      const float4 b4 = *reinterpret_cast<const float4*>(&bo[c0]);
      const float4 q4 = *reinterpret_cast<const float4*>(&query[(size_t)row * kD + c0]);
      float4 o;
      o.x = acc[mi][nj][0] + b4.x + q4.x;
      o.y = acc[mi][nj][1] + b4.y + q4.y;
      o.z = acc[mi][nj][2] + b4.z + q4.z;
      o.w = acc[mi][nj][3] + b4.w + q4.w;
      *reinterpret_cast<float4*>(&Xout[(size_t)row * kD + c0]) = o;
    }
  }
}

// ---------- LayerNorm (in place) ----------
__global__ __launch_bounds__(256, 4)
void k_ln(float* __restrict__ Y, const float* __restrict__ gamma,
          const float* __restrict__ beta) {
  const int row = blockIdx.x;
  float* __restrict__ x = Y + (size_t)row * kD;
  const int tid = threadIdx.x;
  const float4 v = reinterpret_cast<const float4*>(x)[tid];
  float s = v.x + v.y + v.z + v.w;
  float sq = v.x * v.x + v.y * v.y + v.z * v.z + v.w * v.w;
#pragma unroll
  for (int mk = 1; mk < 64; mk <<= 1) {
    s += __shfl_xor(s, mk, 64);
    sq += __shfl_xor(sq, mk, 64);
  }
  __shared__ float ss[4], ssq[4];
  if ((tid & 63) == 0) { ss[tid >> 6] = s; ssq[tid >> 6] = sq; }
  __syncthreads();
  s = ss[0] + ss[1] + ss[2] + ss[3];
  sq = ssq[0] + ssq[1] + ssq[2] + ssq[3];
  const float mu = s * (1.f / kD);
  const float rstd = rsqrtf(sq * (1.f / kD) - mu * mu + kEps);
  const float4 g = reinterpret_cast<const float4*>(gamma)[tid];
  const float4 bb = reinterpret_cast<const float4*>(beta)[tid];
  float4 o;
  o.x = (v.x - mu) * rstd * g.x + bb.x;
  o.y = (v.y - mu) * rstd * g.y + bb.y;
  o.z = (v.z - mu) * rstd * g.z + bb.z;
  o.w = (v.w - mu) * rstd * g.w + bb.w;
  reinterpret_cast<float4*>(x)[tid] = o;
}

extern "C" void kernel_launch(void* const* d_in, const int* in_sizes, int n_in,
                              void* d_out, int out_size, void* d_ws, size_t ws_size,
                              hipStream_t stream) {
  (void)in_sizes; (void)n_in; (void)out_size; (void)ws_size;
  const float* query = (const float*)d_in[0];
  const float* key_i = (const float*)d_in[1];
  const float* value = (const float*)d_in[2];
  const float* Wq = (const float*)d_in[3];
  const float* bq = (const float*)d_in[4];
  const float* Wk = (const float*)d_in[5];
  const float* bk = (const float*)d_in[6];
  const float* Wv = (const float*)d_in[7];
  const float* bv = (const float*)d_in[8];
  const float* Wo = (const float*)d_in[9];
  const float* bo = (const float*)d_in[10];
  const float* gamma = (const float*)d_in[11];
  const float* beta = (const float*)d_in[12];

  float* y_out = (float*)d_out;                       // [2,2048,1024]
  float* attn_out = y_out + (size_t)kBS * kD;         // [2,16,2048,2048]

  u16* Xbq = (u16*)d_ws;
  u16* Xbk = Xbq + (size_t)kBS * kD;
  u16* Xbv = Xbk + (size_t)kBS * kD;
  u16* Wtq = Xbv + (size_t)kBS * kD;
  u16* Wtk = Wtq + (size_t)kD * kD;
  u16* Wtv = Wtk + (size_t)kD * kD;
  u16* Wto = Wtv + (size_t)kD * kD;
  u16* Qw  = Wto + (size_t)kD * kD;
  u16* Kw  = Qw + (size_t)kBH * kS * kDK;
  u16* Vtw = Kw + (size_t)kBH * kS * kDK;
  u16* Cw  = Xbq;   // alias: Xbq dead after k_proj

  k_cvt_x<<<dim3(2048, 3), 256, 0, stream>>>(query, key_i, value, Xbq, Xbk, Xbv);
  k_cvt_w<<<dim3(16, 16, 4), 256, 0, stream>>>(Wq, Wk, Wv, Wo, Wtq, Wtk, Wtv, Wto);
  k_proj<<<dim3(kD / 128, kBS / 128, 3), 256, 0, stream>>>(
      Xbq, Xbk, Xbv, Wtq, Wtk, Wtv, bq, bk, bv, Qw, Kw, Vtw);
  k_attn<<<dim3(kS / 128, kBH), 256, 0, stream>>>(Qw, Kw, Vtw, attn_out, Cw);
  k_oproj<<<dim3(kD / 128, kBS / 128), 256, 0, stream>>>(Cw, Wto, bo, query, y_out);
  k_ln<<<dim3(kBS), 256, 0, stream>>>(y_out, gamma, beta);
}